// Round 6
// baseline (35.781 us; speedup 1.0000x reference)
//
#include <hip/hip_runtime.h>

// MPS batched contraction: out[b] = (e0^T * Π_i M_i(x[b,i]))[0]
// R6: 16x16x32 MFMA. Per site (transposed GEMM): D[d,b] = Σ_k AmatT[d,k]U[k,b],
// k = 2l+p (64 values -> 2 k-halves of 32), d = 0..31 (2 d-halves of 16).
// A-op frag (dhalf,khalf): row d=16*dhalf+(lane&15), k=32*khalf+(lane>>4)*8+e.
// B-op frag khalf: col b=lane&15, same k mapping.
// C/D: col=lane&15, row=(lane>>4)*4+reg (m89-verified).
// Chain property: U_khalf[e] = acc_khalf[e>>1] * x[e&1], SAME LANE.
// Why: R1-R5 pinned the bottleneck as dependency latency at 2 waves/SIMD;
// 16-col waves give 4096 waves (4/SIMD) + two independent 2-deep MFMA chains
// per wave = 8 concurrent chains/SIMD, and halve per-site VALU.

typedef _Float16 half8 __attribute__((ext_vector_type(8)));
typedef float floatx4 __attribute__((ext_vector_type(4)));
typedef float f32x4 __attribute__((ext_vector_type(4)));

#define NSITES 64
// LDS chunk: 8 sites * 4 frags * (64 lanes * 8 halfs) = 16384 halfs = 32KB
#define CHUNK_ELEMS 16384

// Pre-pack A (fp32 [64][32][2][32]) -> fragment-ordered fp16, one site/block.
// Af[((site*4+f)*64 + lane)*8 + e] = (f16) A[site][k>>1][k&1][d],
//   f = dhalf*2 + khalf, d = 16*dhalf + (lane&15), k = 32*khalf + (lane>>4)*8 + e
__global__ void mps_prep_afrag(const float* __restrict__ A, _Float16* __restrict__ Af) {
    __shared__ float sA[2048];          // A[site]: [32][2][32] f32 = 8KB
    const int site = blockIdx.x;
    const int tid  = threadIdx.x;       // 0..255
#pragma unroll
    for (int i = 0; i < 8; ++i) sA[tid + 256 * i] = A[site * 2048 + tid + 256 * i];
    __syncthreads();
    const int f     = tid >> 6;         // 0..3 = dhalf*2 + khalf
    const int lane  = tid & 63;
    const int d     = 16 * (f >> 1) + (lane & 15);
    const int kbase = 32 * (f & 1) + (lane >> 4) * 8;
    half8 v;
#pragma unroll
    for (int e = 0; e < 8; ++e)
        v[e] = (_Float16)sA[(kbase + e) * 32 + d];
    reinterpret_cast<half8*>(Af)[(site * 4 + f) * 64 + lane] = v;
}

// Build one U-frag from one acc half (f32 mul + RNE cvt; same numerics as
// R1-R5, absmax 0.0117).
#define FRAGU(U, AC, X0, X1)                                                  \
    {                                                                         \
        float c0_ = AC[0], c1_ = AC[1], c2_ = AC[2], c3_ = AC[3];             \
        U[0] = (_Float16)(c0_ * (X0)); U[1] = (_Float16)(c0_ * (X1));         \
        U[2] = (_Float16)(c1_ * (X0)); U[3] = (_Float16)(c1_ * (X1));         \
        U[4] = (_Float16)(c2_ * (X0)); U[5] = (_Float16)(c2_ * (X1));         \
        U[6] = (_Float16)(c3_ * (X0)); U[7] = (_Float16)(c3_ * (X1));         \
    }

// One site-step: A-frags in slot SL[4] (f = dhalf*2+khalf), acc pair
// (AI0,AI1) -> (AO0,AO1). Two independent 2-deep MFMA chains.
#define STEP(SL, AI0, AI1, AO0, AO1, XB, J)                                   \
    {                                                                         \
        const float x0_ = XB[2 * (J)], x1_ = XB[2 * (J) + 1];                 \
        half8 u0_, u1_;                                                       \
        FRAGU(u0_, AI0, x0_, x1_);                                            \
        FRAGU(u1_, AI1, x0_, x1_);                                            \
        AO0 = __builtin_amdgcn_mfma_f32_16x16x32_f16(SL[0], u0_, zv, 0, 0, 0);   \
        AO1 = __builtin_amdgcn_mfma_f32_16x16x32_f16(SL[2], u0_, zv, 0, 0, 0);   \
        AO0 = __builtin_amdgcn_mfma_f32_16x16x32_f16(SL[1], u1_, AO0, 0, 0, 0);  \
        AO1 = __builtin_amdgcn_mfma_f32_16x16x32_f16(SL[3], u1_, AO1, 0, 0, 0);  \
    }

// Read site S (local to LDS buffer BUF) frags into register slot DST.
#define RDFRAG(DST, BUF, S)                                                   \
    {                                                                         \
        _Pragma("unroll")                                                     \
        for (int f_ = 0; f_ < 4; ++f_)                                        \
            DST[f_] = *(const half8*)&smA[BUF][(((S) * 4 + f_) * 64 + lane) * 8]; \
    }

// Stage chunk C (8 sites, 32 records of 1KB) into LDS buffer BUF.
// 8 waves x 4 records. LDS dest wave-uniform (+lane*16 by HW); src per-lane.
#define STAGE(C, BUF)                                                         \
    {                                                                         \
        _Pragma("unroll")                                                     \
        for (int r_ = 0; r_ < 4; ++r_) {                                      \
            const int rec_ = r_ * 8 + wid;                                    \
            const _Float16* g_ = Af + (size_t)(C) * CHUNK_ELEMS + rec_ * 512 + lane * 8; \
            __builtin_amdgcn_global_load_lds(                                 \
                (const __attribute__((address_space(1))) void*)g_,            \
                (__attribute__((address_space(3))) void*)&smA[BUF][rec_ * 512], \
                16, 0, 0);                                                    \
        }                                                                     \
    }

// Load one 16-float x octet (8 sites' (x0,x1) pairs). Lane groups share rows
// -> 16 distinct 64B lines per instr (coalescer merges duplicates).
#define LOADX(DST, OCT)                                                       \
    {                                                                         \
        f32x4 t0_ = xp[(OCT) * 4 + 0];                                        \
        f32x4 t1_ = xp[(OCT) * 4 + 1];                                        \
        f32x4 t2_ = xp[(OCT) * 4 + 2];                                        \
        f32x4 t3_ = xp[(OCT) * 4 + 3];                                        \
        DST[0]  = t0_[0]; DST[1]  = t0_[1]; DST[2]  = t0_[2]; DST[3]  = t0_[3]; \
        DST[4]  = t1_[0]; DST[5]  = t1_[1]; DST[6]  = t1_[2]; DST[7]  = t1_[3]; \
        DST[8]  = t2_[0]; DST[9]  = t2_[1]; DST[10] = t2_[2]; DST[11] = t2_[3]; \
        DST[12] = t3_[0]; DST[13] = t3_[1]; DST[14] = t3_[2]; DST[15] = t3_[3]; \
    }

// One 8-site chunk reading LDS buffer BUF; stages chunk C+1 into the other
// buffer and prefetches the next x octet up front. acc ping-pongs a<->n.
#define CHUNK_BODY(C, BUF, XCUR, XNEXT, DO_NEXT)                              \
    {                                                                         \
        if (DO_NEXT) { STAGE((C) + 1, 1 - (BUF)); LOADX(XNEXT, (C) + 1); }    \
        STEP(F0, a0, a1, n0, n1, XCUR, 0) RDFRAG(F0, BUF, 2)                  \
        STEP(F1, n0, n1, a0, a1, XCUR, 1) RDFRAG(F1, BUF, 3)                  \
        STEP(F0, a0, a1, n0, n1, XCUR, 2) RDFRAG(F0, BUF, 4)                  \
        STEP(F1, n0, n1, a0, a1, XCUR, 3) RDFRAG(F1, BUF, 5)                  \
        STEP(F0, a0, a1, n0, n1, XCUR, 4) RDFRAG(F0, BUF, 6)                  \
        STEP(F1, n0, n1, a0, a1, XCUR, 5) RDFRAG(F1, BUF, 7)                  \
        STEP(F0, a0, a1, n0, n1, XCUR, 6)                                     \
        STEP(F1, n0, n1, a0, a1, XCUR, 7)                                     \
        __syncthreads();                                                      \
        if (DO_NEXT) { RDFRAG(F0, 1 - (BUF), 0) RDFRAG(F1, 1 - (BUF), 1) }    \
    }

__global__ __launch_bounds__(512, 4) void mps_main(const float* __restrict__ x,
                                                   const _Float16* __restrict__ Af,
                                                   float* __restrict__ out) {
    __shared__ __align__(16) _Float16 smA[2][CHUNK_ELEMS];   // 2 x 32KB = 64KB

    const int lane = threadIdx.x & 63;
    const int wid  = threadIdx.x >> 6;              // 0..7
    const int row0 = (blockIdx.x * 8 + wid) * 16;   // 16 batch rows per wave
    const int b    = row0 + (lane & 15);

    const f32x4* xp = reinterpret_cast<const f32x4*>(x + (size_t)b * (NSITES * 2));

    floatx4 zv;
#pragma unroll
    for (int i = 0; i < 4; ++i) zv[i] = 0.f;

    // acc pair: a0 holds left[l=(lane>>4)*4+reg], a1 holds left[16+...]
    floatx4 a0, a1, n0, n1;
#pragma unroll
    for (int i = 0; i < 4; ++i) { a0[i] = 0.f; a1[i] = 0.f; n0[i] = 0.f; n1[i] = 0.f; }
    if (lane < 16) a0[0] = 1.f;     // left0 = e0 (l=0 -> h0, group 0, reg 0)

    float xa[16], xb2[16];
    half8 F0[4], F1[4];

    STAGE(0, 0);
    LOADX(xa, 0);
    __syncthreads();
    RDFRAG(F0, 0, 0)
    RDFRAG(F1, 0, 1)

    CHUNK_BODY(0, 0, xa,  xb2, 1)
    CHUNK_BODY(1, 1, xb2, xa,  1)
    CHUNK_BODY(2, 0, xa,  xb2, 1)
    CHUNK_BODY(3, 1, xb2, xa,  1)
    CHUNK_BODY(4, 0, xa,  xb2, 1)
    CHUNK_BODY(5, 1, xb2, xa,  1)
    CHUNK_BODY(6, 0, xa,  xb2, 1)
    CHUNK_BODY(7, 1, xb2, xa,  0)

    // out[b] = left_final[l=0] = a0 reg0 at lane group 0
    if (lane < 16) out[row0 + lane] = a0[0];
}

extern "C" void kernel_launch(void* const* d_in, const int* in_sizes, int n_in,
                              void* d_out, int out_size, void* d_ws, size_t ws_size,
                              hipStream_t stream) {
    const float* x = (const float*)d_in[0];   // [65536][64][2] f32
    const float* A = (const float*)d_in[1];   // [64][32][2][32] f32
    float* outp = (float*)d_out;              // [65536] f32
    _Float16* Af = (_Float16*)d_ws;           // 256 KB fragment-ordered fp16

    hipLaunchKernelGGL(mps_prep_afrag, dim3(NSITES), dim3(256), 0, stream, A, Af);
    hipLaunchKernelGGL(mps_main, dim3(65536 / 128), dim3(512), 0, stream, x, Af, outp);
}